// Round 4
// baseline (353.684 us; speedup 1.0000x reference)
//
#include <hip/hip_runtime.h>
#include <hip/hip_bf16.h>
#include <math.h>

// Problem constants
#define BB 512
#define SS 32
#define DD 256
#define HH 4
#define DHH 64
#define PP 3
#define EE 8
#define KTOP 2
#define HID 1024
#define TT (BB*SS)          // 16384
#define CAP 8192            // 2*T*K/E
#define TD ((size_t)TT*DD)  // 4194304

typedef short short8 __attribute__((ext_vector_type(8)));
typedef float f32x4 __attribute__((ext_vector_type(4)));

__device__ __forceinline__ float wred(float v) {
#pragma unroll
  for (int off = 32; off; off >>= 1) v += __shfl_xor(v, off, 64);
  return v;
}

__device__ __forceinline__ float f4c(const float4& f, int u) {
  return (u == 0) ? f.x : (u == 1) ? f.y : (u == 2) ? f.z : f.w;
}

__device__ __forceinline__ unsigned short f2b(float f) {
  union { float f; unsigned u; } x; x.f = f;
  unsigned r = x.u + 0x7fffu + ((x.u >> 16) & 1u);
  return (unsigned short)(r >> 16);
}

__device__ __forceinline__ float b2f(unsigned short u) {
  union { unsigned u; float f; } x; x.u = ((unsigned)u) << 16;
  return x.f;
}

// tanh-approx gelu (max |err| ~3e-3 in working range; well under 0.098 budget)
__device__ __forceinline__ float gelu_f(float x) {
  float t = 0.7978845608f * x + 0.0356774081f * x * x * x;
  t = fminf(10.f, fmaxf(-10.f, t));
  float e = __expf(2.f * t);
  float th = (e - 1.f) / (e + 1.f);
  return 0.5f * x * (1.f + th);
}

// ---------------- LN1 ----------------
__global__ void k_ln(const float* __restrict__ x, const float* __restrict__ w,
                     const float* __restrict__ b, float* __restrict__ h) {
  int t = blockIdx.x * 4 + (threadIdx.x >> 6);
  int lane = threadIdx.x & 63;
  float4 xv = reinterpret_cast<const float4*>(x + (size_t)t * DD)[lane];
  float s1 = xv.x + xv.y + xv.z + xv.w;
  float s2 = xv.x*xv.x + xv.y*xv.y + xv.z*xv.z + xv.w*xv.w;
  s1 = wred(s1); s2 = wred(s2);
  float m = s1 * (1.f/256.f);
  float var = s2 * (1.f/256.f) - m*m;
  float rs = rsqrtf(var + 1e-6f);
  float4 wv = reinterpret_cast<const float4*>(w)[lane];
  float4 bv = reinterpret_cast<const float4*>(b)[lane];
  float4 o;
  o.x = (xv.x-m)*rs*wv.x + bv.x;
  o.y = (xv.y-m)*rs*wv.y + bv.y;
  o.z = (xv.z-m)*rs*wv.z + bv.z;
  o.w = (xv.w-m)*rs*wv.w + bv.w;
  reinterpret_cast<float4*>(h + (size_t)t * DD)[lane] = o;
}

// ---------------- positional attention (rank-1 in q) ----------------
__global__ void k_pos(const float* __restrict__ pos, const float* __restrict__ p1w,
                      const float* __restrict__ p1b, const float* __restrict__ p2w,
                      const float* __restrict__ p2b, const float* __restrict__ headw,
                      float* __restrict__ pa) {
  int b = blockIdx.x;
  int tid = threadIdx.x;  // 128 = 32 s * 4 h
  __shared__ float ph[HH][SS];
  __shared__ float ex[HH][SS];
  int s = tid >> 2, hd = tid & 3;
  const float* pp = pos + ((size_t)b * SS + s) * PP;
  float p0 = pp[0], p1 = pp[1], p2 = pp[2];
  float t0 = fmaxf(0.f, p0*p1w[0] + p1*p1w[3] + p2*p1w[6] + p1b[0]);
  float t1 = fmaxf(0.f, p0*p1w[1] + p1*p1w[4] + p2*p1w[7] + p1b[1]);
  float t2 = fmaxf(0.f, p0*p1w[2] + p1*p1w[5] + p2*p1w[8] + p1b[2]);
  float acc = 0.f;
#pragma unroll
  for (int c = 0; c < 32; ++c) {
    float pf = t0*p2w[c] + t1*p2w[32+c] + t2*p2w[64+c] + p2b[c];
    acc += pf * headw[c*4 + hd];
  }
  ph[hd][s] = acc;
  __syncthreads();
  if (tid < 4) {
    int h2 = tid;
    float mx = -1e30f;
    for (int j = 0; j < 32; ++j) mx = fmaxf(mx, -ph[h2][j]);
    float sum = 0.f;
    for (int j = 0; j < 32; ++j) { float e = expf(-ph[h2][j] - mx); ex[h2][j] = e; sum += e; }
    float inv = 1.f / sum;
    for (int j = 0; j < 32; ++j) pa[((size_t)b*HH + h2)*SS + j] = ex[h2][j] * inv;
  }
}

// ---------------- QKV GEMM: [T,256] x [256,768] ----------------
__global__ __launch_bounds__(256) void k_qkv(const float* __restrict__ h,
        const float* __restrict__ qw, const float* __restrict__ kw, const float* __restrict__ vw,
        float* __restrict__ q, float* __restrict__ k, float* __restrict__ v) {
  int m0 = blockIdx.x * 64;
  int n0 = blockIdx.y * 64;
  int wsel = n0 >> 8;
  int c0 = n0 & 255;
  const float* W = (wsel == 0) ? qw : (wsel == 1) ? kw : vw;
  float* OUT = (wsel == 0) ? q : (wsel == 1) ? k : v;
  __shared__ float As[64*20];
  __shared__ float Bs[16*64];
  int tid = threadIdx.x;
  int tr = tid >> 4, tc = tid & 15;
  float acc[4][4] = {};
  for (int k0 = 0; k0 < 256; k0 += 16) {
    {
      int r = tid >> 2, kk = (tid & 3) * 4;
      *reinterpret_cast<float4*>(&As[r*20 + kk]) =
        *reinterpret_cast<const float4*>(h + (size_t)(m0 + r)*DD + k0 + kk);
      int r2 = tid >> 4, cc = (tid & 15) * 4;
      *reinterpret_cast<float4*>(&Bs[r2*64 + cc]) =
        *reinterpret_cast<const float4*>(W + (size_t)(k0 + r2)*DD + c0 + cc);
    }
    __syncthreads();
#pragma unroll
    for (int kk4 = 0; kk4 < 4; ++kk4) {
      float4 a[4];
#pragma unroll
      for (int r = 0; r < 4; ++r)
        a[r] = *reinterpret_cast<float4*>(&As[(tr*4 + r)*20 + kk4*4]);
#pragma unroll
      for (int u = 0; u < 4; ++u) {
        float4 bv = *reinterpret_cast<float4*>(&Bs[(kk4*4 + u)*64 + tc*4]);
#pragma unroll
        for (int r = 0; r < 4; ++r) {
          float av = f4c(a[r], u);
          acc[r][0] += av*bv.x; acc[r][1] += av*bv.y;
          acc[r][2] += av*bv.z; acc[r][3] += av*bv.w;
        }
      }
    }
    __syncthreads();
  }
#pragma unroll
  for (int r = 0; r < 4; ++r) {
    int t = m0 + tr*4 + r;
    int b = t >> 5, s = t & 31;
    int cg = c0 + tc*4;
    int hd = cg >> 6, d2 = cg & 63;
    float4 ov = make_float4(acc[r][0], acc[r][1], acc[r][2], acc[r][3]);
    *reinterpret_cast<float4*>(OUT + (((size_t)b*HH + hd)*SS + s)*DHH + d2) = ov;
  }
}

// ---------------- attention core per (b,h) ----------------
__global__ __launch_bounds__(256) void k_attn(const float* __restrict__ q, const float* __restrict__ k,
        const float* __restrict__ v, const float* __restrict__ pa, const float* __restrict__ gate_p,
        float* __restrict__ o) {
  int bh = blockIdx.x;
  int b = bh >> 2, hd = bh & 3;
  __shared__ float qs[32][65];
  __shared__ float ks[32][65];
  __shared__ float vs[32][64];
  __shared__ float ssm[32][33];
  __shared__ float pas[32];
  int tid = threadIdx.x;
  const float* qb = q + (size_t)bh * (SS*DHH);
  const float* kb = k + (size_t)bh * (SS*DHH);
  const float* vb = v + (size_t)bh * (SS*DHH);
  for (int it = tid; it < 512; it += 256) {
    int row = it >> 4, col = (it & 15) * 4;
    float4 qv = *reinterpret_cast<const float4*>(qb + row*DHH + col);
    float4 kv = *reinterpret_cast<const float4*>(kb + row*DHH + col);
    float4 vv = *reinterpret_cast<const float4*>(vb + row*DHH + col);
    qs[row][col] = qv.x; qs[row][col+1] = qv.y; qs[row][col+2] = qv.z; qs[row][col+3] = qv.w;
    ks[row][col] = kv.x; ks[row][col+1] = kv.y; ks[row][col+2] = kv.z; ks[row][col+3] = kv.w;
    *reinterpret_cast<float4*>(&vs[row][col]) = vv;
  }
  if (tid < 32) pas[tid] = pa[(size_t)bh * SS + tid];
  __syncthreads();
#pragma unroll
  for (int rr = 0; rr < 4; ++rr) {
    int id = tid + 256*rr;
    int i = id >> 5, j = id & 31;
    float acc = 0.f;
#pragma unroll
    for (int d = 0; d < 64; ++d) acc += qs[i][d] * ks[j][d];
    ssm[i][j] = acc * 0.125f;
  }
  __syncthreads();
  float gs = 1.f / (1.f + expf(-gate_p[hd]));
  float ga = 1.f - gs;
  if (tid < 32) {
    int i = tid;
    float mx = -1e30f;
    for (int j = 0; j < 32; ++j) mx = fmaxf(mx, ssm[i][j]);
    float sum = 0.f;
    float ev[32];
#pragma unroll
    for (int j = 0; j < 32; ++j) { ev[j] = expf(ssm[i][j] - mx); sum += ev[j]; }
    float inv = 1.f / sum;
#pragma unroll
    for (int j = 0; j < 32; ++j) ssm[i][j] = ga * ev[j] * inv + gs * pas[j];
  }
  __syncthreads();
#pragma unroll
  for (int rr = 0; rr < 8; ++rr) {
    int id = tid + 256*rr;
    int i = id >> 6, d = id & 63;
    float acc = 0.f;
#pragma unroll
    for (int j = 0; j < 32; ++j) acc += ssm[i][j] * vs[j][d];
    o[((size_t)b*SS + i)*DD + hd*DHH + d] = acc;
  }
}

// ---------------- out-proj + residual ----------------
__global__ __launch_bounds__(256) void k_outproj(const float* __restrict__ A,
        const float* __restrict__ W, const float* __restrict__ bias,
        const float* __restrict__ x, float* __restrict__ out) {
  int m0 = blockIdx.x * 64;
  int c0 = blockIdx.y * 64;
  __shared__ float As[64*20];
  __shared__ float Bs[16*64];
  int tid = threadIdx.x;
  int tr = tid >> 4, tc = tid & 15;
  float acc[4][4] = {};
  for (int k0 = 0; k0 < 256; k0 += 16) {
    {
      int r = tid >> 2, kk = (tid & 3) * 4;
      *reinterpret_cast<float4*>(&As[r*20 + kk]) =
        *reinterpret_cast<const float4*>(A + (size_t)(m0 + r)*DD + k0 + kk);
      int r2 = tid >> 4, cc = (tid & 15) * 4;
      *reinterpret_cast<float4*>(&Bs[r2*64 + cc]) =
        *reinterpret_cast<const float4*>(W + (size_t)(k0 + r2)*DD + c0 + cc);
    }
    __syncthreads();
#pragma unroll
    for (int kk4 = 0; kk4 < 4; ++kk4) {
      float4 a[4];
#pragma unroll
      for (int r = 0; r < 4; ++r)
        a[r] = *reinterpret_cast<float4*>(&As[(tr*4 + r)*20 + kk4*4]);
#pragma unroll
      for (int u = 0; u < 4; ++u) {
        float4 bv = *reinterpret_cast<float4*>(&Bs[(kk4*4 + u)*64 + tc*4]);
#pragma unroll
        for (int r = 0; r < 4; ++r) {
          float av = f4c(a[r], u);
          acc[r][0] += av*bv.x; acc[r][1] += av*bv.y;
          acc[r][2] += av*bv.z; acc[r][3] += av*bv.w;
        }
      }
    }
    __syncthreads();
  }
#pragma unroll
  for (int r = 0; r < 4; ++r) {
    int t = m0 + tr*4 + r;
    size_t idx = (size_t)t*DD + c0 + tc*4;
    float4 xv = *reinterpret_cast<const float4*>(x + idx);
    float4 bv = *reinterpret_cast<const float4*>(bias + c0 + tc*4);
    float4 ov;
    ov.x = xv.x + acc[r][0] + bv.x;
    ov.y = xv.y + acc[r][1] + bv.y;
    ov.z = xv.z + acc[r][2] + bv.z;
    ov.w = xv.w + acc[r][3] + bv.w;
    *reinterpret_cast<float4*>(out + idx) = ov;
  }
}

// ---------------- LN2 + gate logits + top-2 (fp32 routing, bf16 token emit) ----------------
__global__ void k_gate(const float* __restrict__ xo, const float* __restrict__ w,
                       const float* __restrict__ b, const float* __restrict__ wg,
                       unsigned short* __restrict__ flatb, int* __restrict__ topi,
                       float* __restrict__ gates) {
  int t = blockIdx.x * 4 + (threadIdx.x >> 6);
  int lane = threadIdx.x & 63;
  float4 xv = reinterpret_cast<const float4*>(xo + (size_t)t * DD)[lane];
  float s1 = xv.x + xv.y + xv.z + xv.w;
  float s2 = xv.x*xv.x + xv.y*xv.y + xv.z*xv.z + xv.w*xv.w;
  s1 = wred(s1); s2 = wred(s2);
  float m = s1 * (1.f/256.f);
  float var = s2 * (1.f/256.f) - m*m;
  float rs = rsqrtf(var + 1e-6f);
  float4 wv = reinterpret_cast<const float4*>(w)[lane];
  float4 bv = reinterpret_cast<const float4*>(b)[lane];
  float4 fv;
  fv.x = (xv.x-m)*rs*wv.x + bv.x;
  fv.y = (xv.y-m)*rs*wv.y + bv.y;
  fv.z = (xv.z-m)*rs*wv.z + bv.z;
  fv.w = (xv.w-m)*rs*wv.w + bv.w;
  ushort4 fb;
  fb.x = f2b(fv.x); fb.y = f2b(fv.y); fb.z = f2b(fv.z); fb.w = f2b(fv.w);
  *reinterpret_cast<ushort4*>(flatb + (size_t)t * DD + lane*4) = fb;
  float pe[8] = {};
  const float* wgp = wg + lane*4*EE;
#pragma unroll
  for (int dd = 0; dd < 4; ++dd) {
    float fd = f4c(fv, dd);
#pragma unroll
    for (int e2 = 0; e2 < 8; ++e2) pe[e2] += fd * wgp[dd*EE + e2];
  }
#pragma unroll
  for (int off = 32; off; off >>= 1) {
#pragma unroll
    for (int e2 = 0; e2 < 8; ++e2) pe[e2] += __shfl_xor(pe[e2], off, 64);
  }
  if (lane == 0) {
    float best = -1e30f, second = -1e30f; int bi = 0, si = 0;
#pragma unroll
    for (int e2 = 0; e2 < 8; ++e2) {
      float vv = pe[e2];
      if (vv > best) { second = best; si = bi; best = vv; bi = e2; }
      else if (vv > second) { second = vv; si = e2; }
    }
    float e1 = expf(second - best);
    float inv = 1.f / (1.f + e1);
    topi[t*2+0] = bi; topi[t*2+1] = si;
    gates[t*2+0] = inv; gates[t*2+1] = e1 * inv;
  }
}

// ---------------- dispatch: histogram, scan, position ----------------
__global__ void k_hist(const int* __restrict__ topi, int* __restrict__ bc) {
  __shared__ int cnt[EE];
  int tid = threadIdx.x;
  if (tid < EE) cnt[tid] = 0;
  __syncthreads();
  int e = topi[blockIdx.x*256 + tid];
  atomicAdd(&cnt[e], 1);
  __syncthreads();
  if (tid < EE) bc[blockIdx.x*EE + tid] = cnt[tid];
}

__global__ void k_scan(const int* __restrict__ bc, int* __restrict__ bo, int* __restrict__ cnt) {
  int e = threadIdx.x;
  if (e < EE) {
    int run = 0;
    for (int blk = 0; blk < 128; ++blk) { bo[blk*EE + e] = run; run += bc[blk*EE + e]; }
    cnt[e] = run;
  }
}

__global__ void k_disp(const int* __restrict__ topi, const int* __restrict__ bo,
                       int* __restrict__ ltok, int* __restrict__ slotof) {
  int tid = threadIdx.x;
  int i = blockIdx.x*256 + tid;
  int e = topi[i];
  int wv = tid >> 6, lane = tid & 63;
  __shared__ int wcnt[4][EE];
  unsigned long long lt = (1ull << lane) - 1ull;
  int prefix = 0;
#pragma unroll
  for (int ee = 0; ee < EE; ++ee) {
    unsigned long long mb = __ballot(e == ee);
    if (e == ee) prefix = __popcll(mb & lt);
    if (lane == 0) wcnt[wv][ee] = __popcll(mb);
  }
  __syncthreads();
  int off = bo[blockIdx.x*EE + e];
  for (int w2 = 0; w2 < wv; ++w2) off += wcnt[w2][e];
  int pos = off + prefix;
  if (pos < CAP) { ltok[e*CAP + pos] = i >> 1; slotof[i] = e*CAP + pos; }
  else           { slotof[i] = -1; }
}

// ---------------- weight fp32 -> bf16 fragment-linear conversion ----------------
// Fragment layout: tile (e, kt, nt) = 512 bf16 contiguous; within tile lane l
// (c=l&15, g=l>>4) holds 8 consecutive k: src[e][kt*32+g*8+j][nt*16+c], j=0..7.
__global__ void k_cvtw(const float* __restrict__ src, unsigned short* __restrict__ dst,
                       int K, int N) {
  int idx = blockIdx.x * 256 + threadIdx.x;
  int lane = idx & 63;
  int tile = idx >> 6;
  int ntn = N >> 4;
  int ntk = K >> 5;
  int e = tile / (ntk * ntn);
  int rem = tile - e * (ntk * ntn);
  int kt = rem / ntn;
  int nt = rem - kt * ntn;
  int g = lane >> 4, c = lane & 15;
  const float* s = src + ((size_t)e * K + kt*32 + g*8) * N + nt*16 + c;
  short8 frag;
#pragma unroll
  for (int j = 0; j < 8; ++j) frag[j] = (short)f2b(s[(size_t)j * N]);
  reinterpret_cast<short8*>(dst)[(size_t)tile * 64 + lane] = frag;
}

// ---------------- MFMA expert FFN: 64-token tiles, register weights ----------------
// LDS: A-tile 32KB + H1 16KB = 48KB -> 3 blocks/CU; weights live in VGPRs,
// batch-issued 8 fragments ahead (compiler emits counted vmcnt waits).
__global__ __launch_bounds__(256, 3) void k_expert(
    const unsigned short* __restrict__ flatb, const unsigned short* __restrict__ w1s,
    const float* __restrict__ b1, const unsigned short* __restrict__ w2s,
    const float* __restrict__ b2,
    const int* __restrict__ ltok, const int* __restrict__ cnt,
    unsigned short* __restrict__ ybuf) {
  int e = blockIdx.x & 7;          // expert -> XCD pinning (L2 locality)
  int rt0 = blockIdx.x >> 3;       // 0..127
  int kept = cnt[e]; if (kept > CAP) kept = CAP;
  int r0 = rt0 * 64;
  if (r0 >= kept) return;
  __shared__ short8 AsV[2048];     // 32KB token tile, XOR-swizzled 16B chunks
  __shared__ short8 H1V[1024];     // 16KB h1 chunk (bf16), swizzled
  int tid = threadIdx.x;
  int lane = tid & 63;
  int w = tid >> 6;
  int c = lane & 15, g = lane >> 4;
  // ---- gather 64 token rows (bf16)
  {
    const short8* fb = reinterpret_cast<const short8*>(flatb);
#pragma unroll
    for (int it = 0; it < 8; ++it) {
      int id = tid + it*256;
      int row = id >> 5, ch = id & 31;
      int rr = r0 + row;
      int src = (rr < kept) ? rr : r0;
      int tok = ltok[e*CAP + src];
      AsV[row*32 + (ch ^ (row & 7))] = fb[(size_t)tok*32 + ch];
    }
  }
  const short8* w1v = reinterpret_cast<const short8*>(w1s);
  const short8* w2v = reinterpret_cast<const short8*>(w2s);
  f32x4 y[4][4] = {};
  __syncthreads();
  for (int hc = 0; hc < 8; ++hc) {
    f32x4 hacc[4][2] = {};
    // ---- GEMM1: two half-batches of 4 K-tiles; weights direct to VGPR
#pragma unroll
    for (int half = 0; half < 2; ++half) {
      short8 bfrag[8];
#pragma unroll
      for (int kk = 0; kk < 4; ++kk) {
        int kt = half*4 + kk;
#pragma unroll
        for (int ct = 0; ct < 2; ++ct)
          bfrag[kk*2+ct] = w1v[(size_t)((e*8 + kt)*64 + hc*8 + w*2 + ct)*64 + lane];
      }
#pragma unroll
      for (int kk = 0; kk < 4; ++kk) {
        int kt = half*4 + kk;
        short8 a[4];
#pragma unroll
        for (int rt = 0; rt < 4; ++rt) {
          int row = rt*16 + c;
          a[rt] = AsV[row*32 + ((kt*4 + g) ^ (row & 7))];
        }
        __builtin_amdgcn_s_setprio(1);
#pragma unroll
        for (int ct = 0; ct < 2; ++ct)
#pragma unroll
          for (int rt = 0; rt < 4; ++rt)
            hacc[rt][ct] = __builtin_amdgcn_mfma_f32_16x16x32_bf16(a[rt], bfrag[kk*2+ct], hacc[rt][ct], 0, 0, 0);
        __builtin_amdgcn_s_setprio(0);
      }
    }
    // ---- prefetch first half of GEMM2 weights (latency hides under gelu)
    short8 b2a[8];
#pragma unroll
    for (int kc2 = 0; kc2 < 2; ++kc2)
#pragma unroll
      for (int ct = 0; ct < 4; ++ct)
        b2a[kc2*4+ct] = w2v[(size_t)((e*32 + hc*4 + kc2)*16 + w*4 + ct)*64 + lane];
    // ---- bias + gelu -> H1V (bf16, swizzled)
    {
      unsigned short* h1u = reinterpret_cast<unsigned short*>(H1V);
#pragma unroll
      for (int ct = 0; ct < 2; ++ct) {
        int col = w*32 + ct*16 + c;   // 0..127 within chunk
        float bb = b1[e*HID + hc*128 + col];
#pragma unroll
        for (int rt = 0; rt < 4; ++rt) {
#pragma unroll
          for (int q = 0; q < 4; ++q) {
            int row = rt*16 + g*4 + q;
            float vv = gelu_f(hacc[rt][ct][q] + bb);
            int ch = (col >> 3) ^ (row & 7);
            h1u[row*128 + ch*8 + (col & 7)] = f2b(vv);
          }
        }
      }
    }
    __syncthreads();   // H1V visible to all waves
    // ---- GEMM2: second-half weight prefetch overlaps first-half compute
    short8 b2b[8];
#pragma unroll
    for (int kc2 = 2; kc2 < 4; ++kc2)
#pragma unroll
      for (int ct = 0; ct < 4; ++ct)
        b2b[(kc2-2)*4+ct] = w2v[(size_t)((e*32 + hc*4 + kc2)*16 + w*4 + ct)*64 + lane];
#pragma unroll
    for (int kc2 = 0; kc2 < 4; ++kc2) {
      short8 a2[4];
#pragma unroll
      for (int rt = 0; rt < 4; ++rt) {
        int row = rt*16 + c;
        a2[rt] = H1V[row*16 + ((kc2*4 + g) ^ (row & 7))];
      }
      __builtin_amdgcn_s_setprio(1);
#pragma unroll
      for (int ct = 0; ct < 4; ++ct) {
        short8 bf = (kc2 < 2) ? b2a[kc2*4+ct] : b2b[(kc2-2)*4+ct];
#pragma unroll
        for (int rt = 0; rt < 4; ++rt)
          y[rt][ct] = __builtin_amdgcn_mfma_f32_16x16x32_bf16(a2[rt], bf, y[rt][ct], 0, 0, 0);
      }
      __builtin_amdgcn_s_setprio(0);
    }
    if (hc < 7) __syncthreads();   // protect H1V before next hc's gelu writes
  }
  // ---- epilogue: fold bias, store bf16 rows to ybuf (no atomics)
  float bb2[4];
#pragma unroll
  for (int ct = 0; ct < 4; ++ct) bb2[ct] = b2[e*DD + w*64 + ct*16 + c];
#pragma unroll
  for (int rt = 0; rt < 4; ++rt) {
#pragma unroll
    for (int q = 0; q < 4; ++q) {
      int row = rt*16 + g*4 + q;
      size_t base = (size_t)(e*CAP + r0 + row) * DD;
#pragma unroll
      for (int ct = 0; ct < 4; ++ct) {
        int col = w*64 + ct*16 + c;
        ybuf[base + col] = f2b(y[rt][ct][q] + bb2[ct]);
      }
    }
  }
}

// ---------------- combine: out += g0*y[slot0] + g1*y[slot1] ----------------
__global__ void k_comb(const unsigned short* __restrict__ ybuf, const int* __restrict__ slotof,
                       const float* __restrict__ gates, float* __restrict__ out) {
  int t = blockIdx.x * 4 + (threadIdx.x >> 6);
  int lane = threadIdx.x & 63;
  int s0 = slotof[t*2], s1 = slotof[t*2+1];
  float g0 = gates[t*2], g1 = gates[t*2+1];
  float4 o = reinterpret_cast<float4*>(out + (size_t)t*DD)[lane];
  if (s0 >= 0) {
    ushort4 a = reinterpret_cast<const ushort4*>(ybuf + (size_t)s0*DD)[lane];
    o.x += g0*b2f(a.x); o.y += g0*b2f(a.y); o.z += g0*b2f(a.z); o.w += g0*b2f(a.w);
  }
  if (s1 >= 0) {
    ushort4 a = reinterpret_cast<const ushort4*>(ybuf + (size_t)s1*DD)[lane];
    o.x += g1*b2f(a.x); o.y += g1*b2f(a.y); o.z += g1*b2f(a.z); o.w += g1*b2f(a.w);
  }
  reinterpret_cast<float4*>(out + (size_t)t*DD)[lane] = o;
}

extern "C" void kernel_launch(void* const* d_in, const int* in_sizes, int n_in,
                              void* d_out, int out_size, void* d_ws, size_t ws_size,
                              hipStream_t stream) {
  (void)in_sizes; (void)n_in; (void)out_size; (void)ws_size;
  const float* x    = (const float*)d_in[0];
  const float* pos  = (const float*)d_in[1];
  const float* ln1w = (const float*)d_in[2];
  const float* ln1b = (const float*)d_in[3];
  const float* ln2w = (const float*)d_in[4];
  const float* ln2b = (const float*)d_in[5];
  const float* qw   = (const float*)d_in[6];
  const float* kw   = (const float*)d_in[7];
  const float* vw   = (const float*)d_in[8];
  const float* p1w  = (const float*)d_in[9];
  const float* p1b  = (const float*)d_in[10];
  const float* p2w  = (const float*)d_in[11];
  const float* p2b  = (const float*)d_in[12];
  const float* headw= (const float*)d_in[13];
  const float* gatep= (const float*)d_in[15];
  const float* outw = (const float*)d_in[16];
  const float* outb = (const float*)d_in[17];
  const float* wg   = (const float*)d_in[18];
  const float* ew1  = (const float*)d_in[19];
  const float* eb1  = (const float*)d_in[20];
  const float* ew2  = (const float*)d_in[21];
  const float* eb2  = (const float*)d_in[22];
  float* out = (float*)d_out;

  float* wsf  = (float*)d_ws;
  float* hbuf = wsf;                 // TD floats; reused as attention-out 'o'
  float* qb   = wsf + TD;
  float* kb   = wsf + 2*TD;
  float* vb   = wsf + 3*TD;
  // qb+kb regions (2*TD floats = 33.5MB) reused after k_attn as ybuf:
  unsigned short* ybuf = (unsigned short*)(wsf + TD);     // E*CAP*DD bf16 = 33.5MB
  // region5 (TD floats = 16MB) repurposed: bf16 tokens + bf16 weights
  unsigned short* flatb = (unsigned short*)(wsf + 4*TD);  // T*256 = 8MB
  unsigned short* w1s   = flatb + TD;                     // E*256*1024 = 4MB
  unsigned short* w2s   = w1s + (size_t)EE*DD*HID;        // E*1024*256 = 4MB
  float* pa   = wsf + 5*TD;          // B*H*S = 65536
  float* gates= pa + 65536;          // T*K = 32768
  int* topi   = (int*)(gates + 32768); // 32768
  int* ltok   = topi + 32768;          // 65536
  int* bc     = ltok + 65536;          // 1024
  int* bo     = bc + 1024;             // 1024
  int* cnt    = bo + 1024;             // 8
  int* slotof = cnt + 8;               // 32768

  k_cvtw<<<dim3(1024), dim3(256), 0, stream>>>(ew1, w1s, DD, HID);
  k_cvtw<<<dim3(1024), dim3(256), 0, stream>>>(ew2, w2s, HID, DD);
  k_pos<<<dim3(BB), dim3(128), 0, stream>>>(pos, p1w, p1b, p2w, p2b, headw, pa);
  k_ln<<<dim3(TT/4), dim3(256), 0, stream>>>(x, ln1w, ln1b, hbuf);
  k_qkv<<<dim3(TT/64, 12), dim3(256), 0, stream>>>(hbuf, qw, kw, vw, qb, kb, vb);
  k_attn<<<dim3(BB*HH), dim3(256), 0, stream>>>(qb, kb, vb, pa, gatep, hbuf);
  k_outproj<<<dim3(TT/64, 4), dim3(256), 0, stream>>>(hbuf, outw, outb, x, out);
  k_gate<<<dim3(TT/4), dim3(256), 0, stream>>>(out, ln2w, ln2b, wg, flatb, topi, gates);
  k_hist<<<dim3(128), dim3(256), 0, stream>>>(topi, bc);
  k_scan<<<dim3(1), dim3(64), 0, stream>>>(bc, bo, cnt);
  k_disp<<<dim3(128), dim3(256), 0, stream>>>(topi, bo, ltok, slotof);
  k_expert<<<dim3(EE*128), dim3(256), 0, stream>>>(flatb, w1s, eb1, w2s, eb2,
                                                   ltok, cnt, ybuf);
  k_comb<<<dim3(TT/4), dim3(256), 0, stream>>>(ybuf, slotof, gates, out);
}

// Round 5
// 286.083 us; speedup vs baseline: 1.2363x; 1.2363x over previous
//
#include <hip/hip_runtime.h>
#include <hip/hip_bf16.h>
#include <math.h>

// Problem constants
#define BB 512
#define SS 32
#define DD 256
#define HH 4
#define DHH 64
#define PP 3
#define EE 8
#define KTOP 2
#define HID 1024
#define TT (BB*SS)          // 16384
#define CAP 8192            // 2*T*K/E
#define TD ((size_t)TT*DD)  // 4194304

typedef short short8 __attribute__((ext_vector_type(8)));
typedef float f32x4 __attribute__((ext_vector_type(4)));

__device__ __forceinline__ float wred(float v) {
#pragma unroll
  for (int off = 32; off; off >>= 1) v += __shfl_xor(v, off, 64);
  return v;
}

__device__ __forceinline__ float f4c(const float4& f, int u) {
  return (u == 0) ? f.x : (u == 1) ? f.y : (u == 2) ? f.z : f.w;
}

__device__ __forceinline__ unsigned short f2b(float f) {
  union { float f; unsigned u; } x; x.f = f;
  unsigned r = x.u + 0x7fffu + ((x.u >> 16) & 1u);
  return (unsigned short)(r >> 16);
}

__device__ __forceinline__ float b2f(unsigned short u) {
  union { unsigned u; float f; } x; x.u = ((unsigned)u) << 16;
  return x.f;
}

__device__ __forceinline__ unsigned cvt_pk_bf16(float lo, float hi) {
  unsigned r;
  asm("v_cvt_pk_bf16_f32 %0, %1, %2" : "=v"(r) : "v"(lo), "v"(hi));
  return r;
}

// tanh-approx gelu, exp2 form: 7 VALU + 2 TRANS. Same semantics as the
// R2-R4 version (absmax 0.031 verified); saturation via inf/0 is graceful.
__device__ __forceinline__ float gelu_f(float x) {
  float x2 = x * x;
  // 2*1.4427*(0.7978845608 + 0.0356774081*x2)
  float t2 = x * __builtin_fmaf(x2, 0.102943842f, 2.30212326f);
  float e = __builtin_amdgcn_exp2f(t2);          // e^(2t)
  float r = __builtin_amdgcn_rcpf(e + 1.f);
  float th = __builtin_fmaf(-2.f, r, 1.f);       // tanh(t)
  return 0.5f * x * (1.f + th);
}

// ---------------- LN1 ----------------
__global__ void k_ln(const float* __restrict__ x, const float* __restrict__ w,
                     const float* __restrict__ b, float* __restrict__ h) {
  int t = blockIdx.x * 4 + (threadIdx.x >> 6);
  int lane = threadIdx.x & 63;
  float4 xv = reinterpret_cast<const float4*>(x + (size_t)t * DD)[lane];
  float s1 = xv.x + xv.y + xv.z + xv.w;
  float s2 = xv.x*xv.x + xv.y*xv.y + xv.z*xv.z + xv.w*xv.w;
  s1 = wred(s1); s2 = wred(s2);
  float m = s1 * (1.f/256.f);
  float var = s2 * (1.f/256.f) - m*m;
  float rs = rsqrtf(var + 1e-6f);
  float4 wv = reinterpret_cast<const float4*>(w)[lane];
  float4 bv = reinterpret_cast<const float4*>(b)[lane];
  float4 o;
  o.x = (xv.x-m)*rs*wv.x + bv.x;
  o.y = (xv.y-m)*rs*wv.y + bv.y;
  o.z = (xv.z-m)*rs*wv.z + bv.z;
  o.w = (xv.w-m)*rs*wv.w + bv.w;
  reinterpret_cast<float4*>(h + (size_t)t * DD)[lane] = o;
}

// ---------------- positional attention (rank-1 in q) ----------------
__global__ void k_pos(const float* __restrict__ pos, const float* __restrict__ p1w,
                      const float* __restrict__ p1b, const float* __restrict__ p2w,
                      const float* __restrict__ p2b, const float* __restrict__ headw,
                      float* __restrict__ pa) {
  int b = blockIdx.x;
  int tid = threadIdx.x;  // 128 = 32 s * 4 h
  __shared__ float ph[HH][SS];
  __shared__ float ex[HH][SS];
  int s = tid >> 2, hd = tid & 3;
  const float* pp = pos + ((size_t)b * SS + s) * PP;
  float p0 = pp[0], p1 = pp[1], p2 = pp[2];
  float t0 = fmaxf(0.f, p0*p1w[0] + p1*p1w[3] + p2*p1w[6] + p1b[0]);
  float t1 = fmaxf(0.f, p0*p1w[1] + p1*p1w[4] + p2*p1w[7] + p1b[1]);
  float t2 = fmaxf(0.f, p0*p1w[2] + p1*p1w[5] + p2*p1w[8] + p1b[2]);
  float acc = 0.f;
#pragma unroll
  for (int c = 0; c < 32; ++c) {
    float pf = t0*p2w[c] + t1*p2w[32+c] + t2*p2w[64+c] + p2b[c];
    acc += pf * headw[c*4 + hd];
  }
  ph[hd][s] = acc;
  __syncthreads();
  if (tid < 4) {
    int h2 = tid;
    float mx = -1e30f;
    for (int j = 0; j < 32; ++j) mx = fmaxf(mx, -ph[h2][j]);
    float sum = 0.f;
    for (int j = 0; j < 32; ++j) { float e = expf(-ph[h2][j] - mx); ex[h2][j] = e; sum += e; }
    float inv = 1.f / sum;
    for (int j = 0; j < 32; ++j) pa[((size_t)b*HH + h2)*SS + j] = ex[h2][j] * inv;
  }
}

// ---------------- QKV GEMM: [T,256] x [256,768], 128x64 tiles ----------------
__global__ __launch_bounds__(256) void k_qkv(const float* __restrict__ h,
        const float* __restrict__ qw, const float* __restrict__ kw, const float* __restrict__ vw,
        float* __restrict__ q, float* __restrict__ k, float* __restrict__ v) {
  int m0 = blockIdx.x * 128;
  int wsel = blockIdx.y >> 2;
  int c0 = (blockIdx.y & 3) * 64;
  const float* W = (wsel == 0) ? qw : (wsel == 1) ? kw : vw;
  float* OUT = (wsel == 0) ? q : (wsel == 1) ? k : v;
  __shared__ float As[128*20];
  __shared__ float Bs[16*68];
  int tid = threadIdx.x;
  int tr = tid >> 4, tc = tid & 15;
  float acc[8][4] = {};
  for (int k0 = 0; k0 < 256; k0 += 16) {
    {
      int r = tid >> 1, kk = (tid & 1) * 8;
      *reinterpret_cast<float4*>(&As[r*20 + kk]) =
        *reinterpret_cast<const float4*>(h + (size_t)(m0 + r)*DD + k0 + kk);
      *reinterpret_cast<float4*>(&As[r*20 + kk + 4]) =
        *reinterpret_cast<const float4*>(h + (size_t)(m0 + r)*DD + k0 + kk + 4);
      int r2 = tid >> 4, cc = (tid & 15) * 4;
      *reinterpret_cast<float4*>(&Bs[r2*68 + cc]) =
        *reinterpret_cast<const float4*>(W + (size_t)(k0 + r2)*DD + c0 + cc);
    }
    __syncthreads();
#pragma unroll
    for (int kk4 = 0; kk4 < 4; ++kk4) {
      float4 a[8];
#pragma unroll
      for (int r = 0; r < 8; ++r)
        a[r] = *reinterpret_cast<float4*>(&As[(tr*8 + r)*20 + kk4*4]);
#pragma unroll
      for (int u = 0; u < 4; ++u) {
        float4 bv = *reinterpret_cast<float4*>(&Bs[(kk4*4 + u)*68 + tc*4]);
#pragma unroll
        for (int r = 0; r < 8; ++r) {
          float av = f4c(a[r], u);
          acc[r][0] += av*bv.x; acc[r][1] += av*bv.y;
          acc[r][2] += av*bv.z; acc[r][3] += av*bv.w;
        }
      }
    }
    __syncthreads();
  }
#pragma unroll
  for (int r = 0; r < 8; ++r) {
    int t = m0 + tr*8 + r;
    int b = t >> 5, s = t & 31;
    int cg = c0 + tc*4;
    int hd = cg >> 6, d2 = cg & 63;
    float4 ov = make_float4(acc[r][0], acc[r][1], acc[r][2], acc[r][3]);
    *reinterpret_cast<float4*>(OUT + (((size_t)b*HH + hd)*SS + s)*DHH + d2) = ov;
  }
}

// ---------------- attention core per (b,h) ----------------
__global__ __launch_bounds__(256) void k_attn(const float* __restrict__ q, const float* __restrict__ k,
        const float* __restrict__ v, const float* __restrict__ pa, const float* __restrict__ gate_p,
        float* __restrict__ o) {
  int bh = blockIdx.x;
  int b = bh >> 2, hd = bh & 3;
  __shared__ float qs[32][65];
  __shared__ float ks[32][65];
  __shared__ float vs[32][64];
  __shared__ float ssm[32][33];
  __shared__ float pas[32];
  int tid = threadIdx.x;
  const float* qb = q + (size_t)bh * (SS*DHH);
  const float* kb = k + (size_t)bh * (SS*DHH);
  const float* vb = v + (size_t)bh * (SS*DHH);
  for (int it = tid; it < 512; it += 256) {
    int row = it >> 4, col = (it & 15) * 4;
    float4 qv = *reinterpret_cast<const float4*>(qb + row*DHH + col);
    float4 kv = *reinterpret_cast<const float4*>(kb + row*DHH + col);
    float4 vv = *reinterpret_cast<const float4*>(vb + row*DHH + col);
    qs[row][col] = qv.x; qs[row][col+1] = qv.y; qs[row][col+2] = qv.z; qs[row][col+3] = qv.w;
    ks[row][col] = kv.x; ks[row][col+1] = kv.y; ks[row][col+2] = kv.z; ks[row][col+3] = kv.w;
    *reinterpret_cast<float4*>(&vs[row][col]) = vv;
  }
  if (tid < 32) pas[tid] = pa[(size_t)bh * SS + tid];
  __syncthreads();
#pragma unroll
  for (int rr = 0; rr < 4; ++rr) {
    int id = tid + 256*rr;
    int i = id >> 5, j = id & 31;
    float acc = 0.f;
#pragma unroll
    for (int d = 0; d < 64; ++d) acc += qs[i][d] * ks[j][d];
    ssm[i][j] = acc * 0.125f;
  }
  __syncthreads();
  float gs = 1.f / (1.f + expf(-gate_p[hd]));
  float ga = 1.f - gs;
  if (tid < 32) {
    int i = tid;
    float mx = -1e30f;
    for (int j = 0; j < 32; ++j) mx = fmaxf(mx, ssm[i][j]);
    float sum = 0.f;
    float ev[32];
#pragma unroll
    for (int j = 0; j < 32; ++j) { ev[j] = expf(ssm[i][j] - mx); sum += ev[j]; }
    float inv = 1.f / sum;
#pragma unroll
    for (int j = 0; j < 32; ++j) ssm[i][j] = ga * ev[j] * inv + gs * pas[j];
  }
  __syncthreads();
#pragma unroll
  for (int rr = 0; rr < 8; ++rr) {
    int id = tid + 256*rr;
    int i = id >> 6, d = id & 63;
    float acc = 0.f;
#pragma unroll
    for (int j = 0; j < 32; ++j) acc += ssm[i][j] * vs[j][d];
    o[((size_t)b*SS + i)*DD + hd*DHH + d] = acc;
  }
}

// ---------------- out-proj + residual, 128x64 tiles ----------------
__global__ __launch_bounds__(256) void k_outproj(const float* __restrict__ A,
        const float* __restrict__ W, const float* __restrict__ bias,
        const float* __restrict__ x, float* __restrict__ out) {
  int m0 = blockIdx.x * 128;
  int c0 = blockIdx.y * 64;
  __shared__ float As[128*20];
  __shared__ float Bs[16*68];
  int tid = threadIdx.x;
  int tr = tid >> 4, tc = tid & 15;
  float acc[8][4] = {};
  for (int k0 = 0; k0 < 256; k0 += 16) {
    {
      int r = tid >> 1, kk = (tid & 1) * 8;
      *reinterpret_cast<float4*>(&As[r*20 + kk]) =
        *reinterpret_cast<const float4*>(A + (size_t)(m0 + r)*DD + k0 + kk);
      *reinterpret_cast<float4*>(&As[r*20 + kk + 4]) =
        *reinterpret_cast<const float4*>(A + (size_t)(m0 + r)*DD + k0 + kk + 4);
      int r2 = tid >> 4, cc = (tid & 15) * 4;
      *reinterpret_cast<float4*>(&Bs[r2*68 + cc]) =
        *reinterpret_cast<const float4*>(W + (size_t)(k0 + r2)*DD + c0 + cc);
    }
    __syncthreads();
#pragma unroll
    for (int kk4 = 0; kk4 < 4; ++kk4) {
      float4 a[8];
#pragma unroll
      for (int r = 0; r < 8; ++r)
        a[r] = *reinterpret_cast<float4*>(&As[(tr*8 + r)*20 + kk4*4]);
#pragma unroll
      for (int u = 0; u < 4; ++u) {
        float4 bv = *reinterpret_cast<float4*>(&Bs[(kk4*4 + u)*68 + tc*4]);
#pragma unroll
        for (int r = 0; r < 8; ++r) {
          float av = f4c(a[r], u);
          acc[r][0] += av*bv.x; acc[r][1] += av*bv.y;
          acc[r][2] += av*bv.z; acc[r][3] += av*bv.w;
        }
      }
    }
    __syncthreads();
  }
#pragma unroll
  for (int r = 0; r < 8; ++r) {
    int t = m0 + tr*8 + r;
    size_t idx = (size_t)t*DD + c0 + tc*4;
    float4 xv = *reinterpret_cast<const float4*>(x + idx);
    float4 bv = *reinterpret_cast<const float4*>(bias + c0 + tc*4);
    float4 ov;
    ov.x = xv.x + acc[r][0] + bv.x;
    ov.y = xv.y + acc[r][1] + bv.y;
    ov.z = xv.z + acc[r][2] + bv.z;
    ov.w = xv.w + acc[r][3] + bv.w;
    *reinterpret_cast<float4*>(out + idx) = ov;
  }
}

// ---------------- LN2 + gate logits + top-2 (fp32 routing, bf16 token emit) ----------------
__global__ void k_gate(const float* __restrict__ xo, const float* __restrict__ w,
                       const float* __restrict__ b, const float* __restrict__ wg,
                       unsigned short* __restrict__ flatb, int* __restrict__ topi,
                       float* __restrict__ gates) {
  int t = blockIdx.x * 4 + (threadIdx.x >> 6);
  int lane = threadIdx.x & 63;
  float4 xv = reinterpret_cast<const float4*>(xo + (size_t)t * DD)[lane];
  float s1 = xv.x + xv.y + xv.z + xv.w;
  float s2 = xv.x*xv.x + xv.y*xv.y + xv.z*xv.z + xv.w*xv.w;
  s1 = wred(s1); s2 = wred(s2);
  float m = s1 * (1.f/256.f);
  float var = s2 * (1.f/256.f) - m*m;
  float rs = rsqrtf(var + 1e-6f);
  float4 wv = reinterpret_cast<const float4*>(w)[lane];
  float4 bv = reinterpret_cast<const float4*>(b)[lane];
  float4 fv;
  fv.x = (xv.x-m)*rs*wv.x + bv.x;
  fv.y = (xv.y-m)*rs*wv.y + bv.y;
  fv.z = (xv.z-m)*rs*wv.z + bv.z;
  fv.w = (xv.w-m)*rs*wv.w + bv.w;
  ushort4 fb;
  fb.x = f2b(fv.x); fb.y = f2b(fv.y); fb.z = f2b(fv.z); fb.w = f2b(fv.w);
  *reinterpret_cast<ushort4*>(flatb + (size_t)t * DD + lane*4) = fb;
  float pe[8] = {};
  const float* wgp = wg + lane*4*EE;
#pragma unroll
  for (int dd = 0; dd < 4; ++dd) {
    float fd = f4c(fv, dd);
#pragma unroll
    for (int e2 = 0; e2 < 8; ++e2) pe[e2] += fd * wgp[dd*EE + e2];
  }
#pragma unroll
  for (int off = 32; off; off >>= 1) {
#pragma unroll
    for (int e2 = 0; e2 < 8; ++e2) pe[e2] += __shfl_xor(pe[e2], off, 64);
  }
  if (lane == 0) {
    float best = -1e30f, second = -1e30f; int bi = 0, si = 0;
#pragma unroll
    for (int e2 = 0; e2 < 8; ++e2) {
      float vv = pe[e2];
      if (vv > best) { second = best; si = bi; best = vv; bi = e2; }
      else if (vv > second) { second = vv; si = e2; }
    }
    float e1 = expf(second - best);
    float inv = 1.f / (1.f + e1);
    topi[t*2+0] = bi; topi[t*2+1] = si;
    gates[t*2+0] = inv; gates[t*2+1] = e1 * inv;
  }
}

// ---------------- dispatch: histogram, scan, position ----------------
__global__ void k_hist(const int* __restrict__ topi, int* __restrict__ bc) {
  __shared__ int cnt[EE];
  int tid = threadIdx.x;
  if (tid < EE) cnt[tid] = 0;
  __syncthreads();
  int e = topi[blockIdx.x*256 + tid];
  atomicAdd(&cnt[e], 1);
  __syncthreads();
  if (tid < EE) bc[blockIdx.x*EE + tid] = cnt[tid];
}

__global__ void k_scan(const int* __restrict__ bc, int* __restrict__ bo, int* __restrict__ cnt) {
  int e = threadIdx.x;
  if (e < EE) {
    int run = 0;
    for (int blk = 0; blk < 128; ++blk) { bo[blk*EE + e] = run; run += bc[blk*EE + e]; }
    cnt[e] = run;
  }
}

__global__ void k_disp(const int* __restrict__ topi, const int* __restrict__ bo,
                       int* __restrict__ ltok, int* __restrict__ slotof) {
  int tid = threadIdx.x;
  int i = blockIdx.x*256 + tid;
  int e = topi[i];
  int wv = tid >> 6, lane = tid & 63;
  __shared__ int wcnt[4][EE];
  unsigned long long lt = (1ull << lane) - 1ull;
  int prefix = 0;
#pragma unroll
  for (int ee = 0; ee < EE; ++ee) {
    unsigned long long mb = __ballot(e == ee);
    if (e == ee) prefix = __popcll(mb & lt);
    if (lane == 0) wcnt[wv][ee] = __popcll(mb);
  }
  __syncthreads();
  int off = bo[blockIdx.x*EE + e];
  for (int w2 = 0; w2 < wv; ++w2) off += wcnt[w2][e];
  int pos = off + prefix;
  if (pos < CAP) { ltok[e*CAP + pos] = i >> 1; slotof[i] = e*CAP + pos; }
  else           { slotof[i] = -1; }
}

// ---------------- weight fp32 -> bf16 fragment-linear conversion ----------------
// Fragment layout: tile (e, kt, nt) = 512 bf16 contiguous; within tile lane l
// (c=l&15, g=l>>4) holds 8 consecutive k: src[e][kt*32+g*8+j][nt*16+c], j=0..7.
__global__ void k_cvtw(const float* __restrict__ src, unsigned short* __restrict__ dst,
                       int K, int N) {
  int idx = blockIdx.x * 256 + threadIdx.x;
  int lane = idx & 63;
  int tile = idx >> 6;
  int ntn = N >> 4;
  int ntk = K >> 5;
  int e = tile / (ntk * ntn);
  int rem = tile - e * (ntk * ntn);
  int kt = rem / ntn;
  int nt = rem - kt * ntn;
  int g = lane >> 4, c = lane & 15;
  const float* s = src + ((size_t)e * K + kt*32 + g*8) * N + nt*16 + c;
  short8 frag;
#pragma unroll
  for (int j = 0; j < 8; ++j) frag[j] = (short)f2b(s[(size_t)j * N]);
  reinterpret_cast<short8*>(dst)[(size_t)tile * 64 + lane] = frag;
}

// ---------------- MFMA expert FFN v5: 8-wave blocks, swapped GEMM1 ----------------
// GEMM1: D[hid][tok] = mfma(w1frag, tokfrag) — wave w owns hid slice w*16 of the
// 128-hid chunk (hacc = 16 regs). h1 -> cvt_pk -> one b64 LDS write per ctT.
// GEMM2: waves split (tok x2, dd x4); y[2][4] = 32 regs. 2 barriers per hc.
__global__ __launch_bounds__(512, 4) void k_expert(
    const unsigned short* __restrict__ flatb, const unsigned short* __restrict__ w1s,
    const float* __restrict__ b1, const unsigned short* __restrict__ w2s,
    const float* __restrict__ b2,
    const int* __restrict__ ltok, const int* __restrict__ cnt,
    unsigned short* __restrict__ ybuf) {
  int e = blockIdx.x & 7;          // expert -> XCD pinning (L2 locality)
  int rt0 = blockIdx.x >> 3;       // 0..127
  int kept = cnt[e]; if (kept > CAP) kept = CAP;
  int r0 = rt0 * 64;
  if (r0 >= kept) return;
  __shared__ short8 AsV[2048];     // 32KB token tile, XOR-swizzled 16B chunks
  __shared__ short8 H1V[1024];     // 16KB h1 chunk [64 tok][128 hid] bf16, swizzled
  int tid = threadIdx.x;           // 0..511
  int lane = tid & 63;
  int w = tid >> 6;                // wave 0..7
  int c = lane & 15, g = lane >> 4;
  int ts = w & 1, dq = w >> 1;     // GEMM2 roles: tok-half, dd-quarter
  // ---- gather 64 token rows (bf16)
  {
    const short8* fb = reinterpret_cast<const short8*>(flatb);
#pragma unroll
    for (int it = 0; it < 4; ++it) {
      int id = tid + it*512;
      int row = id >> 5, ch = id & 31;
      int rr = r0 + row;
      int src = (rr < kept) ? rr : r0;
      int tok = ltok[e*CAP + src];
      AsV[row*32 + (ch ^ (row & 7))] = fb[(size_t)tok*32 + ch];
    }
  }
  const short8* w1v = reinterpret_cast<const short8*>(w1s);
  const short8* w2v = reinterpret_cast<const short8*>(w2s);
  f32x4 y[2][4] = {};
  __syncthreads();
  for (int hc = 0; hc < 8; ++hc) {
    // ---- GEMM1: hid slice w*16 (frag tile nt = hc*8+w), all 64 tokens
    f32x4 hacc[4] = {};
    short8 wf[8];
#pragma unroll
    for (int kt = 0; kt < 8; ++kt)
      wf[kt] = w1v[((size_t)(e*8 + kt)*64 + hc*8 + w)*64 + lane];
#pragma unroll
    for (int kt = 0; kt < 8; ++kt) {
      __builtin_amdgcn_s_setprio(1);
#pragma unroll
      for (int ctT = 0; ctT < 4; ++ctT) {
        short8 a = AsV[(ctT*16 + c)*32 + ((kt*4 + g) ^ (c & 7))];
        hacc[ctT] = __builtin_amdgcn_mfma_f32_16x16x32_bf16(wf[kt], a, hacc[ctT], 0, 0, 0);
      }
      __builtin_amdgcn_s_setprio(0);
    }
    // lane (c,g) of hacc[ctT] holds: tok = ctT*16+c, hid = hc*128 + w*16 + g*4 + q
    float4 b1v = *reinterpret_cast<const float4*>(b1 + e*HID + hc*128 + w*16 + g*4);
    __syncthreads();   // (A) previous GEMM2 done reading H1V
    {
      uint2* h1u = reinterpret_cast<uint2*>(H1V);
#pragma unroll
      for (int ctT = 0; ctT < 4; ++ctT) {
        float v0 = gelu_f(hacc[ctT][0] + b1v.x);
        float v1 = gelu_f(hacc[ctT][1] + b1v.y);
        float v2 = gelu_f(hacc[ctT][2] + b1v.z);
        float v3 = gelu_f(hacc[ctT][3] + b1v.w);
        uint2 pk;
        pk.x = cvt_pk_bf16(v0, v1);
        pk.y = cvt_pk_bf16(v2, v3);
        int tok = ctT*16 + c;
        h1u[(tok*32 + w*4 + g) ^ ((c & 7) << 1)] = pk;
      }
    }
    __syncthreads();   // (B) H1V ready
    // ---- GEMM2: y[tok][dd] over this hc's 128-hid slice (k = 4 frags)
#pragma unroll
    for (int hk = 0; hk < 4; ++hk) {
      short8 wg2[4];
#pragma unroll
      for (int ct = 0; ct < 4; ++ct)
        wg2[ct] = w2v[((size_t)(e*32 + hc*4 + hk)*16 + dq*4 + ct)*64 + lane];
      short8 a2[2];
#pragma unroll
      for (int rt = 0; rt < 2; ++rt) {
        int row = (ts*2 + rt)*16 + c;
        a2[rt] = H1V[row*16 + ((hk*4 + g) ^ (c & 7))];
      }
      __builtin_amdgcn_s_setprio(1);
#pragma unroll
      for (int ct = 0; ct < 4; ++ct)
#pragma unroll
        for (int rt = 0; rt < 2; ++rt)
          y[rt][ct] = __builtin_amdgcn_mfma_f32_16x16x32_bf16(a2[rt], wg2[ct], y[rt][ct], 0, 0, 0);
      __builtin_amdgcn_s_setprio(0);
    }
  }
  // ---- epilogue: fold bias, store bf16 rows to ybuf
  float bb2[4];
#pragma unroll
  for (int ct = 0; ct < 4; ++ct) bb2[ct] = b2[e*DD + (dq*4 + ct)*16 + c];
#pragma unroll
  for (int rt = 0; rt < 2; ++rt) {
#pragma unroll
    for (int q = 0; q < 4; ++q) {
      int tok = (ts*2 + rt)*16 + g*4 + q;
      if (r0 + tok < kept) {
        size_t base = (size_t)(e*CAP + r0 + tok) * DD;
#pragma unroll
        for (int ct = 0; ct < 4; ++ct) {
          int dd = (dq*4 + ct)*16 + c;
          ybuf[base + dd] = f2b(y[rt][ct][q] + bb2[ct]);
        }
      }
    }
  }
}

// ---------------- combine: out += g0*y[slot0] + g1*y[slot1] ----------------
__global__ void k_comb(const unsigned short* __restrict__ ybuf, const int* __restrict__ slotof,
                       const float* __restrict__ gates, float* __restrict__ out) {
  int t = blockIdx.x * 4 + (threadIdx.x >> 6);
  int lane = threadIdx.x & 63;
  int s0 = slotof[t*2], s1 = slotof[t*2+1];
  float g0 = gates[t*2], g1 = gates[t*2+1];
  float4 o = reinterpret_cast<float4*>(out + (size_t)t*DD)[lane];
  if (s0 >= 0) {
    ushort4 a = reinterpret_cast<const ushort4*>(ybuf + (size_t)s0*DD)[lane];
    o.x += g0*b2f(a.x); o.y += g0*b2f(a.y); o.z += g0*b2f(a.z); o.w += g0*b2f(a.w);
  }
  if (s1 >= 0) {
    ushort4 a = reinterpret_cast<const ushort4*>(ybuf + (size_t)s1*DD)[lane];
    o.x += g1*b2f(a.x); o.y += g1*b2f(a.y); o.z += g1*b2f(a.z); o.w += g1*b2f(a.w);
  }
  reinterpret_cast<float4*>(out + (size_t)t*DD)[lane] = o;
}

extern "C" void kernel_launch(void* const* d_in, const int* in_sizes, int n_in,
                              void* d_out, int out_size, void* d_ws, size_t ws_size,
                              hipStream_t stream) {
  (void)in_sizes; (void)n_in; (void)out_size; (void)ws_size;
  const float* x    = (const float*)d_in[0];
  const float* pos  = (const float*)d_in[1];
  const float* ln1w = (const float*)d_in[2];
  const float* ln1b = (const float*)d_in[3];
  const float* ln2w = (const float*)d_in[4];
  const float* ln2b = (const float*)d_in[5];
  const float* qw   = (const float*)d_in[6];
  const float* kw   = (const float*)d_in[7];
  const float* vw   = (const float*)d_in[8];
  const float* p1w  = (const float*)d_in[9];
  const float* p1b  = (const float*)d_in[10];
  const float* p2w  = (const float*)d_in[11];
  const float* p2b  = (const float*)d_in[12];
  const float* headw= (const float*)d_in[13];
  const float* gatep= (const float*)d_in[15];
  const float* outw = (const float*)d_in[16];
  const float* outb = (const float*)d_in[17];
  const float* wg   = (const float*)d_in[18];
  const float* ew1  = (const float*)d_in[19];
  const float* eb1  = (const float*)d_in[20];
  const float* ew2  = (const float*)d_in[21];
  const float* eb2  = (const float*)d_in[22];
  float* out = (float*)d_out;

  float* wsf  = (float*)d_ws;
  float* hbuf = wsf;                 // TD floats; reused as attention-out 'o'
  float* qb   = wsf + TD;
  float* kb   = wsf + 2*TD;
  float* vb   = wsf + 3*TD;
  // qb+kb regions (2*TD floats = 33.5MB) reused after k_attn as ybuf:
  unsigned short* ybuf = (unsigned short*)(wsf + TD);     // E*CAP*DD bf16 = 33.5MB
  // region5 (TD floats = 16MB) repurposed: bf16 tokens + bf16 weights
  unsigned short* flatb = (unsigned short*)(wsf + 4*TD);  // T*256 = 8MB
  unsigned short* w1s   = flatb + TD;                     // E*256*1024 = 4MB
  unsigned short* w2s   = w1s + (size_t)EE*DD*HID;        // E*1024*256 = 4MB
  float* pa   = wsf + 5*TD;          // B*H*S = 65536
  float* gates= pa + 65536;          // T*K = 32768
  int* topi   = (int*)(gates + 32768); // 32768
  int* ltok   = topi + 32768;          // 65536
  int* bc     = ltok + 65536;          // 1024
  int* bo     = bc + 1024;             // 1024
  int* cnt    = bo + 1024;             // 8
  int* slotof = cnt + 8;               // 32768

  k_cvtw<<<dim3(1024), dim3(256), 0, stream>>>(ew1, w1s, DD, HID);
  k_cvtw<<<dim3(1024), dim3(256), 0, stream>>>(ew2, w2s, HID, DD);
  k_pos<<<dim3(BB), dim3(128), 0, stream>>>(pos, p1w, p1b, p2w, p2b, headw, pa);
  k_ln<<<dim3(TT/4), dim3(256), 0, stream>>>(x, ln1w, ln1b, hbuf);
  k_qkv<<<dim3(TT/128, 12), dim3(256), 0, stream>>>(hbuf, qw, kw, vw, qb, kb, vb);
  k_attn<<<dim3(BB*HH), dim3(256), 0, stream>>>(qb, kb, vb, pa, gatep, hbuf);
  k_outproj<<<dim3(TT/128, 4), dim3(256), 0, stream>>>(hbuf, outw, outb, x, out);
  k_gate<<<dim3(TT/4), dim3(256), 0, stream>>>(out, ln2w, ln2b, wg, flatb, topi, gates);
  k_hist<<<dim3(128), dim3(256), 0, stream>>>(topi, bc);
  k_scan<<<dim3(1), dim3(64), 0, stream>>>(bc, bo, cnt);
  k_disp<<<dim3(128), dim3(256), 0, stream>>>(topi, bo, ltok, slotof);
  k_expert<<<dim3(EE*128), dim3(512), 0, stream>>>(flatb, w1s, eb1, w2s, eb2,
                                                   ltok, cnt, ybuf);
  k_comb<<<dim3(TT/4), dim3(256), 0, stream>>>(ybuf, slotof, gates, out);
}

// Round 6
// 225.873 us; speedup vs baseline: 1.5659x; 1.2666x over previous
//
#include <hip/hip_runtime.h>
#include <hip/hip_bf16.h>
#include <math.h>

// Problem constants
#define BB 512
#define SS 32
#define DD 256
#define HH 4
#define DHH 64
#define PP 3
#define EE 8
#define KTOP 2
#define HID 1024
#define TT (BB*SS)          // 16384
#define CAP 8192            // 2*T*K/E
#define TD ((size_t)TT*DD)  // 4194304

typedef short short8 __attribute__((ext_vector_type(8)));
typedef float f32x4 __attribute__((ext_vector_type(4)));

#define GLL(gp, lp) __builtin_amdgcn_global_load_lds( \
    (const __attribute__((address_space(1))) void*)(gp), \
    (__attribute__((address_space(3))) void*)(lp), 16, 0, 0)

__device__ __forceinline__ float wred(float v) {
#pragma unroll
  for (int off = 32; off; off >>= 1) v += __shfl_xor(v, off, 64);
  return v;
}

__device__ __forceinline__ float f4c(const float4& f, int u) {
  return (u == 0) ? f.x : (u == 1) ? f.y : (u == 2) ? f.z : f.w;
}

__device__ __forceinline__ unsigned short f2b(float f) {
  union { float f; unsigned u; } x; x.f = f;
  unsigned r = x.u + 0x7fffu + ((x.u >> 16) & 1u);
  return (unsigned short)(r >> 16);
}

__device__ __forceinline__ float b2f(unsigned short u) {
  union { unsigned u; float f; } x; x.u = ((unsigned)u) << 16;
  return x.f;
}

__device__ __forceinline__ unsigned cvt_pk_bf16(float lo, float hi) {
  unsigned r;
  asm("v_cvt_pk_bf16_f32 %0, %1, %2" : "=v"(r) : "v"(lo), "v"(hi));
  return r;
}

// tanh-approx gelu, exp2 form
__device__ __forceinline__ float gelu_f(float x) {
  float x2 = x * x;
  float t2 = x * __builtin_fmaf(x2, 0.102943842f, 2.30212326f);
  float e = __builtin_amdgcn_exp2f(t2);
  float r = __builtin_amdgcn_rcpf(e + 1.f);
  float th = __builtin_fmaf(-2.f, r, 1.f);
  return 0.5f * x * (1.f + th);
}

// ---------------- LN1 ----------------
__global__ void k_ln(const float* __restrict__ x, const float* __restrict__ w,
                     const float* __restrict__ b, float* __restrict__ h) {
  int t = blockIdx.x * 4 + (threadIdx.x >> 6);
  int lane = threadIdx.x & 63;
  float4 xv = reinterpret_cast<const float4*>(x + (size_t)t * DD)[lane];
  float s1 = xv.x + xv.y + xv.z + xv.w;
  float s2 = xv.x*xv.x + xv.y*xv.y + xv.z*xv.z + xv.w*xv.w;
  s1 = wred(s1); s2 = wred(s2);
  float m = s1 * (1.f/256.f);
  float var = s2 * (1.f/256.f) - m*m;
  float rs = rsqrtf(var + 1e-6f);
  float4 wv = reinterpret_cast<const float4*>(w)[lane];
  float4 bv = reinterpret_cast<const float4*>(b)[lane];
  float4 o;
  o.x = (xv.x-m)*rs*wv.x + bv.x;
  o.y = (xv.y-m)*rs*wv.y + bv.y;
  o.z = (xv.z-m)*rs*wv.z + bv.z;
  o.w = (xv.w-m)*rs*wv.w + bv.w;
  reinterpret_cast<float4*>(h + (size_t)t * DD)[lane] = o;
}

// ---------------- positional attention (rank-1 in q) ----------------
__global__ void k_pos(const float* __restrict__ pos, const float* __restrict__ p1w,
                      const float* __restrict__ p1b, const float* __restrict__ p2w,
                      const float* __restrict__ p2b, const float* __restrict__ headw,
                      float* __restrict__ pa) {
  int b = blockIdx.x;
  int tid = threadIdx.x;  // 128 = 32 s * 4 h
  __shared__ float ph[HH][SS];
  __shared__ float ex[HH][SS];
  int s = tid >> 2, hd = tid & 3;
  const float* pp = pos + ((size_t)b * SS + s) * PP;
  float p0 = pp[0], p1 = pp[1], p2 = pp[2];
  float t0 = fmaxf(0.f, p0*p1w[0] + p1*p1w[3] + p2*p1w[6] + p1b[0]);
  float t1 = fmaxf(0.f, p0*p1w[1] + p1*p1w[4] + p2*p1w[7] + p1b[1]);
  float t2 = fmaxf(0.f, p0*p1w[2] + p1*p1w[5] + p2*p1w[8] + p1b[2]);
  float acc = 0.f;
#pragma unroll
  for (int c = 0; c < 32; ++c) {
    float pf = t0*p2w[c] + t1*p2w[32+c] + t2*p2w[64+c] + p2b[c];
    acc += pf * headw[c*4 + hd];
  }
  ph[hd][s] = acc;
  __syncthreads();
  if (tid < 4) {
    int h2 = tid;
    float mx = -1e30f;
    for (int j = 0; j < 32; ++j) mx = fmaxf(mx, -ph[h2][j]);
    float sum = 0.f;
    for (int j = 0; j < 32; ++j) { float e = expf(-ph[h2][j] - mx); ex[h2][j] = e; sum += e; }
    float inv = 1.f / sum;
    for (int j = 0; j < 32; ++j) pa[((size_t)b*HH + h2)*SS + j] = ex[h2][j] * inv;
  }
}

// ---------------- fp32 -> frag-linear hi/lo split (tokens) ----------------
// dst layout: short8 index ((mt*2 + h)*8 + kt)*64 + lane ; h=0 hi, 1 lo
// lane: c=lane&15 -> row (token mt*16+c), g=lane>>4 -> k-chunk (kt*32+g*8+j)
__global__ void k_cvta(const float* __restrict__ src, unsigned short* __restrict__ dst) {
  int tile = blockIdx.x * 4 + (threadIdx.x >> 6);   // mt*8 + kt
  int lane = threadIdx.x & 63;
  int mt = tile >> 3, kt = tile & 7;
  int c = lane & 15, g = lane >> 4;
  const float* s = src + ((size_t)mt*16 + c)*DD + kt*32 + g*8;
  float4 x0 = *reinterpret_cast<const float4*>(s);
  float4 x1 = *reinterpret_cast<const float4*>(s + 4);
  float xs[8] = {x0.x, x0.y, x0.z, x0.w, x1.x, x1.y, x1.z, x1.w};
  short8 hi, lo;
#pragma unroll
  for (int j = 0; j < 8; ++j) {
    unsigned short hb = f2b(xs[j]);
    hi[j] = (short)hb;
    lo[j] = (short)f2b(xs[j] - b2f(hb));
  }
  short8* d = reinterpret_cast<short8*>(dst);
  d[((size_t)mt*16 + kt)*64 + lane] = hi;
  d[((size_t)mt*16 + 8 + kt)*64 + lane] = lo;
}

// ---------------- qkv weights fp32 -> combined frag hi/lo ----------------
// dst: tile (kt,nt) nt 0..47 (q:0-15,k:16-31,v:32-47): short8 idx tile*128 + (hi?0:64) + lane
__global__ void k_cvtw3(const float* __restrict__ qw, const float* __restrict__ kw,
                        const float* __restrict__ vw, unsigned short* __restrict__ dst) {
  int tile = blockIdx.x * 4 + (threadIdx.x >> 6);   // kt*48 + nt
  int lane = threadIdx.x & 63;
  int kt = tile / 48, nt = tile % 48;
  int c = lane & 15, g = lane >> 4;
  const float* W = (nt < 16) ? qw : (nt < 32) ? kw : vw;
  int col = (nt & 15) * 16 + c;
  const float* s = W + ((size_t)kt*32 + g*8)*DD + col;
  short8 hi, lo;
#pragma unroll
  for (int j = 0; j < 8; ++j) {
    float x = s[(size_t)j * DD];
    unsigned short hb = f2b(x);
    hi[j] = (short)hb;
    lo[j] = (short)f2b(x - b2f(hb));
  }
  short8* d = reinterpret_cast<short8*>(dst);
  d[(size_t)tile*128 + lane] = hi;
  d[(size_t)tile*128 + 64 + lane] = lo;
}

// ---------------- single weight [256,256] fp32 -> frag hi/lo (16 nt) ----------------
__global__ void k_cvtw1(const float* __restrict__ W, unsigned short* __restrict__ dst) {
  int tile = blockIdx.x * 4 + (threadIdx.x >> 6);   // kt*16 + nt, 128 tiles
  int lane = threadIdx.x & 63;
  int kt = tile >> 4, nt = tile & 15;
  int c = lane & 15, g = lane >> 4;
  int col = nt * 16 + c;
  const float* s = W + ((size_t)kt*32 + g*8)*DD + col;
  short8 hi, lo;
#pragma unroll
  for (int j = 0; j < 8; ++j) {
    float x = s[(size_t)j * DD];
    unsigned short hb = f2b(x);
    hi[j] = (short)hb;
    lo[j] = (short)f2b(x - b2f(hb));
  }
  short8* d = reinterpret_cast<short8*>(dst);
  d[(size_t)tile*128 + lane] = hi;
  d[(size_t)tile*128 + 64 + lane] = lo;
}

// ---------------- QKV via split-bf16 MFMA: D = Ah*Bh + Al*Bh + Ah*Bl ----------------
// 8 waves, M=64 tokens/block, N=768 (wave w: cols w*96..+95). A hi/lo in LDS.
__global__ __launch_bounds__(512, 2) void k_qkvm(
    const unsigned short* __restrict__ tfrag, const unsigned short* __restrict__ wqkvf,
    float* __restrict__ q, float* __restrict__ k, float* __restrict__ v) {
  extern __shared__ short8 AF[];          // 4096 short8 = 64KB
  int tid = threadIdx.x, lane = tid & 63, w = tid >> 6;
  int c = lane & 15, g = lane >> 4;
  const short8* tf = reinterpret_cast<const short8*>(tfrag) + (size_t)blockIdx.x * 4096;
#pragma unroll
  for (int i = 0; i < 8; ++i)
    GLL(tf + i*512 + w*64 + lane, AF + i*512 + w*64);
  const short8* wfv = reinterpret_cast<const short8*>(wqkvf);
  f32x4 acc[4][6] = {};
  __syncthreads();
  for (int kt = 0; kt < 8; ++kt) {
    short8 bh[6], bl[6];
#pragma unroll
    for (int n = 0; n < 6; ++n) {
      const short8* bp = wfv + ((size_t)kt*48 + w*6 + n)*128;
      bh[n] = bp[lane]; bl[n] = bp[64 + lane];
    }
    short8 ah[4], al[4];
#pragma unroll
    for (int mt = 0; mt < 4; ++mt) {
      ah[mt] = AF[(mt*16 + kt)*64 + lane];
      al[mt] = AF[(mt*16 + 8 + kt)*64 + lane];
    }
    __builtin_amdgcn_s_setprio(1);
#pragma unroll
    for (int n = 0; n < 6; ++n)
#pragma unroll
      for (int mt = 0; mt < 4; ++mt) {
        acc[mt][n] = __builtin_amdgcn_mfma_f32_16x16x32_bf16(ah[mt], bh[n], acc[mt][n], 0, 0, 0);
        acc[mt][n] = __builtin_amdgcn_mfma_f32_16x16x32_bf16(al[mt], bh[n], acc[mt][n], 0, 0, 0);
        acc[mt][n] = __builtin_amdgcn_mfma_f32_16x16x32_bf16(ah[mt], bl[n], acc[mt][n], 0, 0, 0);
      }
    __builtin_amdgcn_s_setprio(0);
  }
#pragma unroll
  for (int n = 0; n < 6; ++n) {
    int col = w*96 + n*16 + c;
    int wsel = col >> 8, cc = col & 255;
    int hd = cc >> 6, d2 = cc & 63;
    float* OUT = (wsel == 0) ? q : (wsel == 1) ? k : v;
#pragma unroll
    for (int mt = 0; mt < 4; ++mt) {
#pragma unroll
      for (int r = 0; r < 4; ++r) {
        int tok = (blockIdx.x*4 + mt)*16 + g*4 + r;
        int b = tok >> 5, s = tok & 31;
        OUT[(((size_t)b*HH + hd)*SS + s)*DHH + d2] = acc[mt][n][r];
      }
    }
  }
}

// ---------------- out-proj via split-bf16 MFMA + residual ----------------
__global__ __launch_bounds__(512, 2) void k_outm(
    const unsigned short* __restrict__ afrag, const unsigned short* __restrict__ wof,
    const float* __restrict__ xres, const float* __restrict__ bias,
    float* __restrict__ out) {
  extern __shared__ short8 AF[];          // 4096 short8 = 64KB
  int tid = threadIdx.x, lane = tid & 63, w = tid >> 6;
  int c = lane & 15, g = lane >> 4;
  const short8* tf = reinterpret_cast<const short8*>(afrag) + (size_t)blockIdx.x * 4096;
#pragma unroll
  for (int i = 0; i < 8; ++i)
    GLL(tf + i*512 + w*64 + lane, AF + i*512 + w*64);
  const short8* wfv = reinterpret_cast<const short8*>(wof);
  f32x4 acc[4][2] = {};
  __syncthreads();
  for (int kt = 0; kt < 8; ++kt) {
    short8 bh[2], bl[2];
#pragma unroll
    for (int n = 0; n < 2; ++n) {
      const short8* bp = wfv + ((size_t)kt*16 + w*2 + n)*128;
      bh[n] = bp[lane]; bl[n] = bp[64 + lane];
    }
    short8 ah[4], al[4];
#pragma unroll
    for (int mt = 0; mt < 4; ++mt) {
      ah[mt] = AF[(mt*16 + kt)*64 + lane];
      al[mt] = AF[(mt*16 + 8 + kt)*64 + lane];
    }
    __builtin_amdgcn_s_setprio(1);
#pragma unroll
    for (int n = 0; n < 2; ++n)
#pragma unroll
      for (int mt = 0; mt < 4; ++mt) {
        acc[mt][n] = __builtin_amdgcn_mfma_f32_16x16x32_bf16(ah[mt], bh[n], acc[mt][n], 0, 0, 0);
        acc[mt][n] = __builtin_amdgcn_mfma_f32_16x16x32_bf16(al[mt], bh[n], acc[mt][n], 0, 0, 0);
        acc[mt][n] = __builtin_amdgcn_mfma_f32_16x16x32_bf16(ah[mt], bl[n], acc[mt][n], 0, 0, 0);
      }
    __builtin_amdgcn_s_setprio(0);
  }
#pragma unroll
  for (int n = 0; n < 2; ++n) {
    int col = w*32 + n*16 + c;
    float bb = bias[col];
#pragma unroll
    for (int mt = 0; mt < 4; ++mt) {
#pragma unroll
      for (int r = 0; r < 4; ++r) {
        int tok = (blockIdx.x*4 + mt)*16 + g*4 + r;
        size_t idx = (size_t)tok*DD + col;
        out[idx] = xres[idx] + acc[mt][n][r] + bb;
      }
    }
  }
}

// ---------------- attention core per (b,h) ----------------
__global__ __launch_bounds__(256) void k_attn(const float* __restrict__ q, const float* __restrict__ k,
        const float* __restrict__ v, const float* __restrict__ pa, const float* __restrict__ gate_p,
        float* __restrict__ o) {
  int bh = blockIdx.x;
  int b = bh >> 2, hd = bh & 3;
  __shared__ float qs[32][65];
  __shared__ float ks[32][65];
  __shared__ float vs[32][64];
  __shared__ float ssm[32][33];
  __shared__ float pas[32];
  int tid = threadIdx.x;
  const float* qb = q + (size_t)bh * (SS*DHH);
  const float* kb = k + (size_t)bh * (SS*DHH);
  const float* vb = v + (size_t)bh * (SS*DHH);
  for (int it = tid; it < 512; it += 256) {
    int row = it >> 4, col = (it & 15) * 4;
    float4 qv = *reinterpret_cast<const float4*>(qb + row*DHH + col);
    float4 kv = *reinterpret_cast<const float4*>(kb + row*DHH + col);
    float4 vv = *reinterpret_cast<const float4*>(vb + row*DHH + col);
    qs[row][col] = qv.x; qs[row][col+1] = qv.y; qs[row][col+2] = qv.z; qs[row][col+3] = qv.w;
    ks[row][col] = kv.x; ks[row][col+1] = kv.y; ks[row][col+2] = kv.z; ks[row][col+3] = kv.w;
    *reinterpret_cast<float4*>(&vs[row][col]) = vv;
  }
  if (tid < 32) pas[tid] = pa[(size_t)bh * SS + tid];
  __syncthreads();
#pragma unroll
  for (int rr = 0; rr < 4; ++rr) {
    int id = tid + 256*rr;
    int i = id >> 5, j = id & 31;
    float acc = 0.f;
#pragma unroll
    for (int d = 0; d < 64; ++d) acc += qs[i][d] * ks[j][d];
    ssm[i][j] = acc * 0.125f;
  }
  __syncthreads();
  float gs = 1.f / (1.f + expf(-gate_p[hd]));
  float ga = 1.f - gs;
  if (tid < 32) {
    int i = tid;
    float mx = -1e30f;
    for (int j = 0; j < 32; ++j) mx = fmaxf(mx, ssm[i][j]);
    float sum = 0.f;
    float ev[32];
#pragma unroll
    for (int j = 0; j < 32; ++j) { ev[j] = expf(ssm[i][j] - mx); sum += ev[j]; }
    float inv = 1.f / sum;
#pragma unroll
    for (int j = 0; j < 32; ++j) ssm[i][j] = ga * ev[j] * inv + gs * pas[j];
  }
  __syncthreads();
#pragma unroll
  for (int rr = 0; rr < 8; ++rr) {
    int id = tid + 256*rr;
    int i = id >> 6, d = id & 63;
    float acc = 0.f;
#pragma unroll
    for (int j = 0; j < 32; ++j) acc += ssm[i][j] * vs[j][d];
    o[((size_t)b*SS + i)*DD + hd*DHH + d] = acc;
  }
}

// ---------------- LN2 + gate logits + top-2 (fp32 routing, bf16 token emit) ----------------
__global__ void k_gate(const float* __restrict__ xo, const float* __restrict__ w,
                       const float* __restrict__ b, const float* __restrict__ wg,
                       unsigned short* __restrict__ flatb, int* __restrict__ topi,
                       float* __restrict__ gates) {
  int t = blockIdx.x * 4 + (threadIdx.x >> 6);
  int lane = threadIdx.x & 63;
  float4 xv = reinterpret_cast<const float4*>(xo + (size_t)t * DD)[lane];
  float s1 = xv.x + xv.y + xv.z + xv.w;
  float s2 = xv.x*xv.x + xv.y*xv.y + xv.z*xv.z + xv.w*xv.w;
  s1 = wred(s1); s2 = wred(s2);
  float m = s1 * (1.f/256.f);
  float var = s2 * (1.f/256.f) - m*m;
  float rs = rsqrtf(var + 1e-6f);
  float4 wv = reinterpret_cast<const float4*>(w)[lane];
  float4 bv = reinterpret_cast<const float4*>(b)[lane];
  float4 fv;
  fv.x = (xv.x-m)*rs*wv.x + bv.x;
  fv.y = (xv.y-m)*rs*wv.y + bv.y;
  fv.z = (xv.z-m)*rs*wv.z + bv.z;
  fv.w = (xv.w-m)*rs*wv.w + bv.w;
  ushort4 fb;
  fb.x = f2b(fv.x); fb.y = f2b(fv.y); fb.z = f2b(fv.z); fb.w = f2b(fv.w);
  *reinterpret_cast<ushort4*>(flatb + (size_t)t * DD + lane*4) = fb;
  float pe[8] = {};
  const float* wgp = wg + lane*4*EE;
#pragma unroll
  for (int dd = 0; dd < 4; ++dd) {
    float fd = f4c(fv, dd);
#pragma unroll
    for (int e2 = 0; e2 < 8; ++e2) pe[e2] += fd * wgp[dd*EE + e2];
  }
#pragma unroll
  for (int off = 32; off; off >>= 1) {
#pragma unroll
    for (int e2 = 0; e2 < 8; ++e2) pe[e2] += __shfl_xor(pe[e2], off, 64);
  }
  if (lane == 0) {
    float best = -1e30f, second = -1e30f; int bi = 0, si = 0;
#pragma unroll
    for (int e2 = 0; e2 < 8; ++e2) {
      float vv = pe[e2];
      if (vv > best) { second = best; si = bi; best = vv; bi = e2; }
      else if (vv > second) { second = vv; si = e2; }
    }
    float e1 = expf(second - best);
    float inv = 1.f / (1.f + e1);
    topi[t*2+0] = bi; topi[t*2+1] = si;
    gates[t*2+0] = inv; gates[t*2+1] = e1 * inv;
  }
}

// ---------------- dispatch: histogram, scan, position ----------------
__global__ void k_hist(const int* __restrict__ topi, int* __restrict__ bc) {
  __shared__ int cnt[EE];
  int tid = threadIdx.x;
  if (tid < EE) cnt[tid] = 0;
  __syncthreads();
  int e = topi[blockIdx.x*256 + tid];
  atomicAdd(&cnt[e], 1);
  __syncthreads();
  if (tid < EE) bc[blockIdx.x*EE + tid] = cnt[tid];
}

__global__ void k_scan(const int* __restrict__ bc, int* __restrict__ bo, int* __restrict__ cnt) {
  int e = threadIdx.x;
  if (e < EE) {
    int run = 0;
    for (int blk = 0; blk < 128; ++blk) { bo[blk*EE + e] = run; run += bc[blk*EE + e]; }
    cnt[e] = run;
  }
}

__global__ void k_disp(const int* __restrict__ topi, const int* __restrict__ bo,
                       int* __restrict__ ltok, int* __restrict__ slotof) {
  int tid = threadIdx.x;
  int i = blockIdx.x*256 + tid;
  int e = topi[i];
  int wv = tid >> 6, lane = tid & 63;
  __shared__ int wcnt[4][EE];
  unsigned long long lt = (1ull << lane) - 1ull;
  int prefix = 0;
#pragma unroll
  for (int ee = 0; ee < EE; ++ee) {
    unsigned long long mb = __ballot(e == ee);
    if (e == ee) prefix = __popcll(mb & lt);
    if (lane == 0) wcnt[wv][ee] = __popcll(mb);
  }
  __syncthreads();
  int off = bo[blockIdx.x*EE + e];
  for (int w2 = 0; w2 < wv; ++w2) off += wcnt[w2][e];
  int pos = off + prefix;
  if (pos < CAP) { ltok[e*CAP + pos] = i >> 1; slotof[i] = e*CAP + pos; }
  else           { slotof[i] = -1; }
}

// ---------------- expert weight fp32 -> bf16 fragment-linear ----------------
__global__ void k_cvtw(const float* __restrict__ src, unsigned short* __restrict__ dst,
                       int K, int N) {
  int idx = blockIdx.x * 256 + threadIdx.x;
  int lane = idx & 63;
  int tile = idx >> 6;
  int ntn = N >> 4;
  int ntk = K >> 5;
  int e = tile / (ntk * ntn);
  int rem = tile - e * (ntk * ntn);
  int kt = rem / ntn;
  int nt = rem - kt * ntn;
  int g = lane >> 4, c = lane & 15;
  const float* s = src + ((size_t)e * K + kt*32 + g*8) * N + nt*16 + c;
  short8 frag;
#pragma unroll
  for (int j = 0; j < 8; ++j) frag[j] = (short)f2b(s[(size_t)j * N]);
  reinterpret_cast<short8*>(dst)[(size_t)tile * 64 + lane] = frag;
}

// ---------------- MFMA expert FFN: 8-wave blocks, swapped GEMM1 ----------------
__global__ __launch_bounds__(512, 4) void k_expert(
    const unsigned short* __restrict__ flatb, const unsigned short* __restrict__ w1s,
    const float* __restrict__ b1, const unsigned short* __restrict__ w2s,
    const float* __restrict__ b2,
    const int* __restrict__ ltok, const int* __restrict__ cnt,
    unsigned short* __restrict__ ybuf) {
  int e = blockIdx.x & 7;
  int rt0 = blockIdx.x >> 3;
  int kept = cnt[e]; if (kept > CAP) kept = CAP;
  int r0 = rt0 * 64;
  if (r0 >= kept) return;
  __shared__ short8 AsV[2048];
  __shared__ short8 H1V[1024];
  int tid = threadIdx.x;
  int lane = tid & 63;
  int w = tid >> 6;
  int c = lane & 15, g = lane >> 4;
  int ts = w & 1, dq = w >> 1;
  {
    const short8* fb = reinterpret_cast<const short8*>(flatb);
#pragma unroll
    for (int it = 0; it < 4; ++it) {
      int id = tid + it*512;
      int row = id >> 5, ch = id & 31;
      int rr = r0 + row;
      int src = (rr < kept) ? rr : r0;
      int tok = ltok[e*CAP + src];
      AsV[row*32 + (ch ^ (row & 7))] = fb[(size_t)tok*32 + ch];
    }
  }
  const short8* w1v = reinterpret_cast<const short8*>(w1s);
  const short8* w2v = reinterpret_cast<const short8*>(w2s);
  f32x4 y[2][4] = {};
  __syncthreads();
  for (int hc = 0; hc < 8; ++hc) {
    f32x4 hacc[4] = {};
    short8 wf[8];
#pragma unroll
    for (int kt = 0; kt < 8; ++kt)
      wf[kt] = w1v[((size_t)(e*8 + kt)*64 + hc*8 + w)*64 + lane];
#pragma unroll
    for (int kt = 0; kt < 8; ++kt) {
      __builtin_amdgcn_s_setprio(1);
#pragma unroll
      for (int ctT = 0; ctT < 4; ++ctT) {
        short8 a = AsV[(ctT*16 + c)*32 + ((kt*4 + g) ^ (c & 7))];
        hacc[ctT] = __builtin_amdgcn_mfma_f32_16x16x32_bf16(wf[kt], a, hacc[ctT], 0, 0, 0);
      }
      __builtin_amdgcn_s_setprio(0);
    }
    float4 b1v = *reinterpret_cast<const float4*>(b1 + e*HID + hc*128 + w*16 + g*4);
    __syncthreads();
    {
      uint2* h1u = reinterpret_cast<uint2*>(H1V);
#pragma unroll
      for (int ctT = 0; ctT < 4; ++ctT) {
        float v0 = gelu_f(hacc[ctT][0] + b1v.x);
        float v1 = gelu_f(hacc[ctT][1] + b1v.y);
        float v2 = gelu_f(hacc[ctT][2] + b1v.z);
        float v3 = gelu_f(hacc[ctT][3] + b1v.w);
        uint2 pk;
        pk.x = cvt_pk_bf16(v0, v1);
        pk.y = cvt_pk_bf16(v2, v3);
        int tok = ctT*16 + c;
        h1u[(tok*32 + w*4 + g) ^ ((c & 7) << 1)] = pk;
      }
    }
    __syncthreads();
#pragma unroll
    for (int hk = 0; hk < 4; ++hk) {
      short8 wg2[4];
#pragma unroll
      for (int ct = 0; ct < 4; ++ct)
        wg2[ct] = w2v[((size_t)(e*32 + hc*4 + hk)*16 + dq*4 + ct)*64 + lane];
      short8 a2[2];
#pragma unroll
      for (int rt = 0; rt < 2; ++rt) {
        int row = (ts*2 + rt)*16 + c;
        a2[rt] = H1V[row*16 + ((hk*4 + g) ^ (c & 7))];
      }
      __builtin_amdgcn_s_setprio(1);
#pragma unroll
      for (int ct = 0; ct < 4; ++ct)
#pragma unroll
        for (int rt = 0; rt < 2; ++rt)
          y[rt][ct] = __builtin_amdgcn_mfma_f32_16x16x32_bf16(a2[rt], wg2[ct], y[rt][ct], 0, 0, 0);
      __builtin_amdgcn_s_setprio(0);
    }
  }
  float bb2[4];
#pragma unroll
  for (int ct = 0; ct < 4; ++ct) bb2[ct] = b2[e*DD + (dq*4 + ct)*16 + c];
#pragma unroll
  for (int rt = 0; rt < 2; ++rt) {
#pragma unroll
    for (int q = 0; q < 4; ++q) {
      int tok = (ts*2 + rt)*16 + g*4 + q;
      if (r0 + tok < kept) {
        size_t base = (size_t)(e*CAP + r0 + tok) * DD;
#pragma unroll
        for (int ct = 0; ct < 4; ++ct) {
          int dd = (dq*4 + ct)*16 + c;
          ybuf[base + dd] = f2b(y[rt][ct][q] + bb2[ct]);
        }
      }
    }
  }
}

// ---------------- combine: out += g0*y[slot0] + g1*y[slot1] ----------------
__global__ void k_comb(const unsigned short* __restrict__ ybuf, const int* __restrict__ slotof,
                       const float* __restrict__ gates, float* __restrict__ out) {
  int t = blockIdx.x * 4 + (threadIdx.x >> 6);
  int lane = threadIdx.x & 63;
  int s0 = slotof[t*2], s1 = slotof[t*2+1];
  float g0 = gates[t*2], g1 = gates[t*2+1];
  float4 o = reinterpret_cast<float4*>(out + (size_t)t*DD)[lane];
  if (s0 >= 0) {
    ushort4 a = reinterpret_cast<const ushort4*>(ybuf + (size_t)s0*DD)[lane];
    o.x += g0*b2f(a.x); o.y += g0*b2f(a.y); o.z += g0*b2f(a.z); o.w += g0*b2f(a.w);
  }
  if (s1 >= 0) {
    ushort4 a = reinterpret_cast<const ushort4*>(ybuf + (size_t)s1*DD)[lane];
    o.x += g1*b2f(a.x); o.y += g1*b2f(a.y); o.z += g1*b2f(a.z); o.w += g1*b2f(a.w);
  }
  reinterpret_cast<float4*>(out + (size_t)t*DD)[lane] = o;
}

extern "C" void kernel_launch(void* const* d_in, const int* in_sizes, int n_in,
                              void* d_out, int out_size, void* d_ws, size_t ws_size,
                              hipStream_t stream) {
  (void)in_sizes; (void)n_in; (void)out_size; (void)ws_size;
  const float* x    = (const float*)d_in[0];
  const float* pos  = (const float*)d_in[1];
  const float* ln1w = (const float*)d_in[2];
  const float* ln1b = (const float*)d_in[3];
  const float* ln2w = (const float*)d_in[4];
  const float* ln2b = (const float*)d_in[5];
  const float* qw   = (const float*)d_in[6];
  const float* kw   = (const float*)d_in[7];
  const float* vw   = (const float*)d_in[8];
  const float* p1w  = (const float*)d_in[9];
  const float* p1b  = (const float*)d_in[10];
  const float* p2w  = (const float*)d_in[11];
  const float* p2b  = (const float*)d_in[12];
  const float* headw= (const float*)d_in[13];
  const float* gatep= (const float*)d_in[15];
  const float* outw = (const float*)d_in[16];
  const float* outb = (const float*)d_in[17];
  const float* wg   = (const float*)d_in[18];
  const float* ew1  = (const float*)d_in[19];
  const float* eb1  = (const float*)d_in[20];
  const float* ew2  = (const float*)d_in[21];
  const float* eb2  = (const float*)d_in[22];
  float* out = (float*)d_out;

  float* wsf  = (float*)d_ws;
  float* hbuf = wsf;                 // TD floats; LN1 out, then attention out
  float* qb   = wsf + TD;
  float* kb   = wsf + 2*TD;
  float* vb   = wsf + 3*TD;
  unsigned short* ybuf = (unsigned short*)(wsf + TD);     // reuses qb+kb after attn
  unsigned short* flatb = (unsigned short*)(wsf + 4*TD);  // 8MB
  unsigned short* w1s   = flatb + TD;                     // 4MB
  unsigned short* w2s   = w1s + (size_t)EE*DD*HID;        // 4MB
  float* pa   = wsf + 5*TD;            // 65536
  float* gates= pa + 65536;            // 32768
  int* topi   = (int*)(gates + 32768); // 32768
  int* ltok   = topi + 32768;          // 65536
  int* bc     = ltok + 65536;          // 1024
  int* bo     = bc + 1024;             // 1024
  int* cnt    = bo + 1024;             // 8
  int* slotof = cnt + 8;               // 32768
  // frag region: after 5TD + 1M floats
  unsigned short* tfrag = (unsigned short*)(wsf + 5*TD + (1<<20));  // 2*TD shorts = 16.8MB
  unsigned short* wqkvf = tfrag + 2*TD;                             // 393216 shorts
  unsigned short* woutf = wqkvf + 393216;                           // 131072 shorts

  k_cvtw<<<dim3(1024), dim3(256), 0, stream>>>(ew1, w1s, DD, HID);
  k_cvtw<<<dim3(1024), dim3(256), 0, stream>>>(ew2, w2s, HID, DD);
  k_cvtw3<<<dim3(96), dim3(256), 0, stream>>>(qw, kw, vw, wqkvf);
  k_cvtw1<<<dim3(32), dim3(256), 0, stream>>>(outw, woutf);
  k_pos<<<dim3(BB), dim3(128), 0, stream>>>(pos, p1w, p1b, p2w, p2b, headw, pa);
  k_ln<<<dim3(TT/4), dim3(256), 0, stream>>>(x, ln1w, ln1b, hbuf);
  k_cvta<<<dim3(2048), dim3(256), 0, stream>>>(hbuf, tfrag);
  k_qkvm<<<dim3(TT/64), dim3(512), 65536, stream>>>(tfrag, wqkvf, qb, kb, vb);
  k_attn<<<dim3(BB*HH), dim3(256), 0, stream>>>(qb, kb, vb, pa, gatep, hbuf);
  k_cvta<<<dim3(2048), dim3(256), 0, stream>>>(hbuf, tfrag);
  k_outm<<<dim3(TT/64), dim3(512), 65536, stream>>>(tfrag, woutf, x, outb, out);
  k_gate<<<dim3(TT/4), dim3(256), 0, stream>>>(out, ln2w, ln2b, wg, flatb, topi, gates);
  k_hist<<<dim3(128), dim3(256), 0, stream>>>(topi, bc);
  k_scan<<<dim3(1), dim3(64), 0, stream>>>(bc, bo, cnt);
  k_disp<<<dim3(128), dim3(256), 0, stream>>>(topi, bo, ltok, slotof);
  k_expert<<<dim3(EE*128), dim3(512), 0, stream>>>(flatb, w1s, eb1, w2s, eb2,
                                                   ltok, cnt, ybuf);
  k_comb<<<dim3(TT/4), dim3(256), 0, stream>>>(ybuf, slotof, gates, out);
}